// Round 4
// baseline (809.259 us; speedup 1.0000x reference)
//
#include <hip/hip_runtime.h>
#include <hip/hip_bf16.h>
#include <hip/hip_fp16.h>
#include <stdint.h>

// Problem constants (QLoRALinear_34454227649197)
#define M_DIM 16384   // TOK
#define N_DIM 4096    // OUT
#define K_DIM 4096    // IN
#define NGROUP 64     // K_DIM / 64

// NOTE (round-3 forensics): harness normalizes float16 arrays to FLOAT32 on
// device (fp16 absent from dtype table; out_npz 157.8 MB > 134.2 MB fp16-raw
// proves f32 wire format). So: x = const float*, out = float*.

typedef _Float16 f16x8 __attribute__((ext_vector_type(8)));
typedef _Float16 f16x2 __attribute__((ext_vector_type(2)));
typedef float f32x4 __attribute__((ext_vector_type(4)));

// ---------------------------------------------------------------------------
// Kernel 0: Xh[i] = (fp16) x[i]   (exact: x values are fp16-quantized)
// ---------------------------------------------------------------------------
__global__ __launch_bounds__(256) void convert_x_kernel(
    const float* __restrict__ x, _Float16* __restrict__ Xh)
{
    const size_t i = ((size_t)blockIdx.x * 256 + threadIdx.x) * 8;
    const float4 a = *reinterpret_cast<const float4*>(&x[i]);
    const float4 b = *reinterpret_cast<const float4*>(&x[i + 4]);
    f16x8 o;
    o[0] = (_Float16)a.x; o[1] = (_Float16)a.y;
    o[2] = (_Float16)a.z; o[3] = (_Float16)a.w;
    o[4] = (_Float16)b.x; o[5] = (_Float16)b.y;
    o[6] = (_Float16)b.z; o[7] = (_Float16)b.w;
    *reinterpret_cast<f16x8*>(&Xh[i]) = o;
}

// ---------------------------------------------------------------------------
// Kernel 1: W[local n][k] = (q[n0+n][k]-8)*scales[n0+n][k/64]
//                           + sum_r lB[n0+n][r]*lA[r][k]     (fp16 out)
// ---------------------------------------------------------------------------
__global__ __launch_bounds__(256) void dequant_lora_kernel(
    const int* __restrict__ q, const float* __restrict__ sc,
    const float* __restrict__ lA, const float* __restrict__ lB,
    _Float16* __restrict__ W, int n0)
{
    const int t   = threadIdx.x;
    const int o0l = blockIdx.x * 4;        // local chunk row base
    const int o0g = n0 + o0l;              // global OUT row base

    __shared__ float sScale[4][64];
    __shared__ float sB[4][16];
    sScale[t >> 6][t & 63] = sc[(size_t)(o0g + (t >> 6)) * NGROUP + (t & 63)];
    if (t < 64) sB[t >> 4][t & 15] = lB[(size_t)(o0g + (t >> 4)) * 16 + (t & 15)];
    __syncthreads();

    for (int j = 0; j < 8; ++j) {
        const int i = j * 512 + t * 2;      // even; covers [0,4096)
        float l0[4] = {0.f, 0.f, 0.f, 0.f};
        float l1[4] = {0.f, 0.f, 0.f, 0.f};
        #pragma unroll
        for (int r = 0; r < 16; ++r) {
            const float2 a = *reinterpret_cast<const float2*>(&lA[(size_t)r * K_DIM + i]);
            #pragma unroll
            for (int row = 0; row < 4; ++row) {
                l0[row] = fmaf(sB[row][r], a.x, l0[row]);
                l1[row] = fmaf(sB[row][r], a.y, l1[row]);
            }
        }
        const int g = i >> 6;               // i even => i, i+1 same group
        #pragma unroll
        for (int row = 0; row < 4; ++row) {
            const int2 qv = *reinterpret_cast<const int2*>(&q[(size_t)(o0g + row) * K_DIM + i]);
            const float s = sScale[row][g];
            f16x2 h2;
            h2[0] = (_Float16)fmaf((float)(qv.x - 8), s, l0[row]);
            h2[1] = (_Float16)fmaf((float)(qv.y - 8), s, l1[row]);
            *reinterpret_cast<f16x2*>(&W[(size_t)(o0l + row) * K_DIM + i]) = h2;
        }
    }
}

// ---------------------------------------------------------------------------
// Kernel 2: out[m0+.., n0+..] = Xh_chunk @ W_chunk^T   (fp16 in, f32 out)
// 128x128 tile, BK=64, 4 waves (2x2, each 64x64), 16x16x32 f16 MFMA.
// Reg-staged LDS (round-3 structure), linear LDS layout, f32 epilogue.
// ---------------------------------------------------------------------------
__global__ __launch_bounds__(256, 2) void gemm_bt_kernel(
    const _Float16* __restrict__ A,   // Xh chunk, [rows][K]
    const _Float16* __restrict__ B,   // W chunk,  [cols][K]
    float* __restrict__ C,
    int m0, int n0, int nbm, int nbn)
{
    alignas(16) __shared__ _Float16 sA[128 * 64];
    alignas(16) __shared__ _Float16 sB[128 * 64];

    const int t  = threadIdx.x;
    const int l  = t & 63;
    const int w  = t >> 6;
    const int wr = w >> 1;          // wave row (64 C-rows)
    const int wc = w & 1;           // wave col (64 C-cols)

    // m204 bijective XCD swizzle, then tail-safe GROUP_M=8.
    const int nwg  = nbm * nbn;
    const int orig = blockIdx.x;
    const int xcd  = orig & 7;
    const int qq = nwg >> 3, rr = nwg & 7;
    const int wg = (xcd < rr ? xcd * (qq + 1) : rr * (qq + 1) + (xcd - rr) * qq)
                 + (orig >> 3);
    const int gs    = 8 * nbn;
    const int group = wg / gs;
    const int start = group * 8;
    const int gsz   = (nbm - start < 8) ? (nbm - start) : 8;
    const int idg   = wg - group * gs;
    const int bm    = start + idg % gsz;
    const int bn    = idg / gsz;

    const int Mb = bm * 128;        // row within chunk
    const int Nb = bn * 128;        // row within W chunk

    // Staging geometry: thread t -> row (t>>3) of each 32-row group,
    // k-slot (t&7) (8 fp16 = 16 B).
    const int rloc = t >> 3;        // 0..31
    const int slot = t & 7;         // 0..7
    const _Float16* aSrc = A + (size_t)(Mb + rloc) * K_DIM + slot * 8;
    const _Float16* bSrc = B + (size_t)(Nb + rloc) * K_DIM + slot * 8;

    const int r16 = l & 15;
    const int hi  = l >> 4;         // 0..3

    f32x4 acc[4][4] = {};

    for (int k0 = 0; k0 < K_DIM; k0 += 64) {
        bf16x8_dummy:;  // (label unused; keeps diff minimal)
        f16x8 va[4], vb[4];
        #pragma unroll
        for (int n = 0; n < 4; ++n) {
            va[n] = *(const f16x8*)(aSrc + (size_t)(n * 32) * K_DIM + k0);
            vb[n] = *(const f16x8*)(bSrc + (size_t)(n * 32) * K_DIM + k0);
        }
        __syncthreads();   // previous iteration's LDS reads complete
        #pragma unroll
        for (int n = 0; n < 4; ++n) {
            *(f16x8*)&sA[(size_t)(n * 32 + rloc) * 64 + slot * 8] = va[n];
            *(f16x8*)&sB[(size_t)(n * 32 + rloc) * 64 + slot * 8] = vb[n];
        }
        __syncthreads();   // staged data visible to all waves

        #pragma unroll
        for (int s = 0; s < 2; ++s) {
            f16x8 aF[4], bF[4];
            const int ks = (s * 4 + hi) * 8;   // k-slice (frag: k=(l>>4)*8+j)
            #pragma unroll
            for (int i = 0; i < 4; ++i) {
                aF[i] = *(const f16x8*)&sA[(size_t)(wr * 64 + i * 16 + r16) * 64 + ks];
                bF[i] = *(const f16x8*)&sB[(size_t)(wc * 64 + i * 16 + r16) * 64 + ks];
            }
            #pragma unroll
            for (int mi = 0; mi < 4; ++mi)
                #pragma unroll
                for (int ni = 0; ni < 4; ++ni)
                    acc[mi][ni] = __builtin_amdgcn_mfma_f32_16x16x32_f16(
                        aF[mi], bF[ni], acc[mi][ni], 0, 0, 0);
        }
    }

    // Epilogue: C/D layout col = lane&15, row = (lane>>4)*4 + reg. f32 stores.
    #pragma unroll
    for (int mi = 0; mi < 4; ++mi) {
        const int row0 = m0 + Mb + wr * 64 + mi * 16 + hi * 4;
        #pragma unroll
        for (int ni = 0; ni < 4; ++ni) {
            const int col = n0 + Nb + wc * 64 + ni * 16 + r16;
            const f32x4 v = acc[mi][ni];
            #pragma unroll
            for (int u = 0; u < 4; ++u)
                C[(size_t)(row0 + u) * N_DIM + col] = v[u];
        }
    }
}

extern "C" void kernel_launch(void* const* d_in, const int* in_sizes, int n_in,
                              void* d_out, int out_size, void* d_ws, size_t ws_size,
                              hipStream_t stream) {
    const float* x  = (const float*)d_in[0];   // fp16 values promoted to f32
    const int*   q  = (const int*)d_in[1];
    const float* sc = (const float*)d_in[2];
    const float* lA = (const float*)d_in[3];
    const float* lB = (const float*)d_in[4];
    float* out = (float*)d_out;                 // f32 output buffer

    // Workspace layout: [W: colC x K fp16][Xh: rowC x K fp16], chunk-looped.
    const size_t wfull = (size_t)N_DIM * K_DIM * 2;   // 32 MiB
    int colC, rowC;
    if (ws_size >= wfull + (size_t)128 * K_DIM * 2) {
        colC = N_DIM;
        size_t rows = (ws_size - wfull) / ((size_t)K_DIM * 2);
        rowC = (int)((rows / 128) * 128);
        if (rowC > M_DIM) rowC = M_DIM;
    } else {
        size_t half = ws_size / 2;
        colC = (int)((half / ((size_t)K_DIM * 2) / 128) * 128);
        if (colC < 128) colC = 128;
        if (colC > N_DIM) colC = N_DIM;
        size_t rows = (ws_size - (size_t)colC * K_DIM * 2) / ((size_t)K_DIM * 2);
        rowC = (int)((rows / 128) * 128);
        if (rowC < 128) rowC = 128;
        if (rowC > M_DIM) rowC = M_DIM;
    }
    _Float16* W  = (_Float16*)d_ws;
    _Float16* Xh = (_Float16*)d_ws + (size_t)colC * K_DIM;

    for (int n0 = 0; n0 < N_DIM; n0 += colC) {
        int cols = N_DIM - n0; if (cols > colC) cols = colC;
        dequant_lora_kernel<<<cols / 4, 256, 0, stream>>>(q, sc, lA, lB, W, n0);
        for (int m0 = 0; m0 < M_DIM; m0 += rowC) {
            int rows = M_DIM - m0; if (rows > rowC) rows = rowC;
            convert_x_kernel<<<(int)(((size_t)rows * K_DIM) / (256 * 8)), 256, 0, stream>>>(
                x + (size_t)m0 * K_DIM, Xh);
            gemm_bt_kernel<<<(rows / 128) * (cols / 128), 256, 0, stream>>>(
                Xh, W, out, m0, n0, rows / 128, cols / 128);
        }
    }
}

// Round 5
// 629.846 us; speedup vs baseline: 1.2849x; 1.2849x over previous
//
#include <hip/hip_runtime.h>
#include <hip/hip_bf16.h>
#include <hip/hip_fp16.h>
#include <stdint.h>

// Problem constants (QLoRALinear_34454227649197)
#define M_DIM 16384   // TOK
#define N_DIM 4096    // OUT
#define K_DIM 4096    // IN
#define NGROUP 64     // K_DIM / 64

// Harness dtype note (round-3 forensics): float16 arrays are presented as
// FLOAT32 on device. x = const float*, out = float*.

typedef _Float16 f16x8 __attribute__((ext_vector_type(8)));
typedef _Float16 f16x2 __attribute__((ext_vector_type(2)));
typedef float f32x4 __attribute__((ext_vector_type(4)));

typedef __attribute__((address_space(3))) uint32_t lds_u32_t;
typedef const __attribute__((address_space(1))) uint32_t glob_u32_t;

__device__ __forceinline__ void gload16(const void* g, void* l) {
    // global_load_lds_dwordx4: LDS dest = wave-uniform base + lane*16;
    // global source is per-lane (enables pre-swizzled source, rule 21).
    // Validated correct in rounds 1-3 (bit-identical to reg-staged path).
    __builtin_amdgcn_global_load_lds((glob_u32_t*)g, (lds_u32_t*)l, 16, 0, 0);
}

// ---------------------------------------------------------------------------
// Kernel 0: Xh[i] = (fp16) x[i]   (exact: x values are fp16-quantized)
// ---------------------------------------------------------------------------
__global__ __launch_bounds__(256) void convert_x_kernel(
    const float* __restrict__ x, _Float16* __restrict__ Xh)
{
    const size_t i = ((size_t)blockIdx.x * 256 + threadIdx.x) * 8;
    const float4 a = *reinterpret_cast<const float4*>(&x[i]);
    const float4 b = *reinterpret_cast<const float4*>(&x[i + 4]);
    f16x8 o;
    o[0] = (_Float16)a.x; o[1] = (_Float16)a.y;
    o[2] = (_Float16)a.z; o[3] = (_Float16)a.w;
    o[4] = (_Float16)b.x; o[5] = (_Float16)b.y;
    o[6] = (_Float16)b.z; o[7] = (_Float16)b.w;
    *reinterpret_cast<f16x8*>(&Xh[i]) = o;
}

// ---------------------------------------------------------------------------
// Kernel 1: W[local n][k] = (q[n0+n][k]-8)*scales[n0+n][k/64]
//                           + sum_r lB[n0+n][r]*lA[r][k]     (fp16 out)
// ---------------------------------------------------------------------------
__global__ __launch_bounds__(256) void dequant_lora_kernel(
    const int* __restrict__ q, const float* __restrict__ sc,
    const float* __restrict__ lA, const float* __restrict__ lB,
    _Float16* __restrict__ W, int n0)
{
    const int t   = threadIdx.x;
    const int o0l = blockIdx.x * 4;        // local chunk row base
    const int o0g = n0 + o0l;              // global OUT row base

    __shared__ float sScale[4][64];
    __shared__ float sB[4][16];
    sScale[t >> 6][t & 63] = sc[(size_t)(o0g + (t >> 6)) * NGROUP + (t & 63)];
    if (t < 64) sB[t >> 4][t & 15] = lB[(size_t)(o0g + (t >> 4)) * 16 + (t & 15)];
    __syncthreads();

    for (int j = 0; j < 8; ++j) {
        const int i = j * 512 + t * 2;      // even; covers [0,4096)
        float l0[4] = {0.f, 0.f, 0.f, 0.f};
        float l1[4] = {0.f, 0.f, 0.f, 0.f};
        #pragma unroll
        for (int r = 0; r < 16; ++r) {
            const float2 a = *reinterpret_cast<const float2*>(&lA[(size_t)r * K_DIM + i]);
            #pragma unroll
            for (int row = 0; row < 4; ++row) {
                l0[row] = fmaf(sB[row][r], a.x, l0[row]);
                l1[row] = fmaf(sB[row][r], a.y, l1[row]);
            }
        }
        const int g = i >> 6;               // i even => i, i+1 same group
        #pragma unroll
        for (int row = 0; row < 4; ++row) {
            const int2 qv = *reinterpret_cast<const int2*>(&q[(size_t)(o0g + row) * K_DIM + i]);
            const float s = sScale[row][g];
            f16x2 h2;
            h2[0] = (_Float16)fmaf((float)(qv.x - 8), s, l0[row]);
            h2[1] = (_Float16)fmaf((float)(qv.y - 8), s, l1[row]);
            *reinterpret_cast<f16x2*>(&W[(size_t)(o0l + row) * K_DIM + i]) = h2;
        }
    }
}

// ---------------------------------------------------------------------------
// Kernel 2: out[m0+.., n0+..] = Xh_chunk @ W_chunk^T   (fp16 in, f32 out)
// m97 structure: 128x128 tile, BK=64, 4 waves (2x2, each 64x64), 16x16x32
// f16 MFMA, global_load_lds width-16 with PRE-SWIZZLED global source
// (slot^ (row&7)) + swizzled ds_read -> ~2-way (free) LDS banking.
// ---------------------------------------------------------------------------
__global__ __launch_bounds__(256, 2) void gemm_bt_kernel(
    const _Float16* __restrict__ A,   // Xh chunk, [rows][K]
    const _Float16* __restrict__ B,   // W chunk,  [cols][K]
    float* __restrict__ C,
    int m0, int n0, int nbm, int nbn)
{
    alignas(16) __shared__ _Float16 sA[128 * 64];
    alignas(16) __shared__ _Float16 sB[128 * 64];

    const int t  = threadIdx.x;
    const int l  = t & 63;
    const int w  = t >> 6;
    const int wr = w >> 1;          // wave row (64 C-rows)
    const int wc = w & 1;           // wave col (64 C-cols)

    // m204 bijective XCD swizzle, then tail-safe GROUP_M=8.
    const int nwg  = nbm * nbn;
    const int orig = blockIdx.x;
    const int xcd  = orig & 7;
    const int qq = nwg >> 3, rr = nwg & 7;
    const int wg = (xcd < rr ? xcd * (qq + 1) : rr * (qq + 1) + (xcd - rr) * qq)
                 + (orig >> 3);
    const int gs    = 8 * nbn;
    const int group = wg / gs;
    const int start = group * 8;
    const int gsz   = (nbm - start < 8) ? (nbm - start) : 8;
    const int idg   = wg - group * gs;
    const int bm    = start + idg % gsz;
    const int bn    = idg / gsz;

    const int Mb = bm * 128;        // row within A chunk
    const int Nb = bn * 128;        // row within W chunk

    // Staging: thread t -> row rloc = t>>3 (of each 32-row issue), physical
    // slot p = t&7; source k-offset = (p ^ (row&7))*8 elems (inverse swizzle
    // pre-applied on the GLOBAL side; LDS dest stays linear t*16).
    const int rloc = t >> 3;                   // 0..31
    const int kswz = ((t & 7) ^ (rloc & 7)) * 8;
    const _Float16* aSrc = A + (size_t)(Mb + rloc) * K_DIM + kswz;
    const _Float16* bSrc = B + (size_t)(Nb + rloc) * K_DIM + kswz;
    char* ldsA = (char*)sA + t * 16;
    char* ldsB = (char*)sB + t * 16;

    const int r16 = l & 15;
    const int hi  = l >> 4;         // 0..3

    f32x4 acc[4][4] = {};

    for (int k0 = 0; k0 < K_DIM; k0 += 64) {
        #pragma unroll
        for (int n = 0; n < 4; ++n) {
            gload16(aSrc + (size_t)(n * 32) * K_DIM + k0, ldsA + n * 4096);
            gload16(bSrc + (size_t)(n * 32) * K_DIM + k0, ldsB + n * 4096);
        }
        __syncthreads();   // vmcnt(0) drain precedes s_barrier

        #pragma unroll
        for (int s = 0; s < 2; ++s) {
            f16x8 aF[4], bF[4];
            // logical k-slot (s*4+hi) lives at physical slot (s*4+hi)^(row&7);
            // row&7 == r16&7 for all fragment rows (offsets are multiples of 8).
            const int swz = ((s * 4 + hi) ^ (r16 & 7)) * 16;   // bytes
            #pragma unroll
            for (int i = 0; i < 4; ++i) {
                aF[i] = *(const f16x8*)((const char*)sA + (wr * 64 + i * 16 + r16) * 128 + swz);
                bF[i] = *(const f16x8*)((const char*)sB + (wc * 64 + i * 16 + r16) * 128 + swz);
            }
            #pragma unroll
            for (int mi = 0; mi < 4; ++mi)
                #pragma unroll
                for (int ni = 0; ni < 4; ++ni)
                    acc[mi][ni] = __builtin_amdgcn_mfma_f32_16x16x32_f16(
                        aF[mi], bF[ni], acc[mi][ni], 0, 0, 0);
        }
        __syncthreads();
    }

    // Epilogue: C/D layout col = lane&15, row = (lane>>4)*4 + reg. f32 stores.
    #pragma unroll
    for (int mi = 0; mi < 4; ++mi) {
        const int row0 = m0 + Mb + wr * 64 + mi * 16 + hi * 4;
        #pragma unroll
        for (int ni = 0; ni < 4; ++ni) {
            const int col = n0 + Nb + wc * 64 + ni * 16 + r16;
            const f32x4 v = acc[mi][ni];
            #pragma unroll
            for (int u = 0; u < 4; ++u)
                C[(size_t)(row0 + u) * N_DIM + col] = v[u];
        }
    }
}

extern "C" void kernel_launch(void* const* d_in, const int* in_sizes, int n_in,
                              void* d_out, int out_size, void* d_ws, size_t ws_size,
                              hipStream_t stream) {
    const float* x  = (const float*)d_in[0];   // fp16 values promoted to f32
    const int*   q  = (const int*)d_in[1];
    const float* sc = (const float*)d_in[2];
    const float* lA = (const float*)d_in[3];
    const float* lB = (const float*)d_in[4];
    float* out = (float*)d_out;                 // f32 output buffer

    // Workspace layout: [W: colC x K fp16][Xh: rowC x K fp16], chunk-looped.
    const size_t wfull = (size_t)N_DIM * K_DIM * 2;   // 32 MiB
    int colC, rowC;
    if (ws_size >= wfull + (size_t)128 * K_DIM * 2) {
        colC = N_DIM;
        size_t rows = (ws_size - wfull) / ((size_t)K_DIM * 2);
        rowC = (int)((rows / 128) * 128);
        if (rowC > M_DIM) rowC = M_DIM;
    } else {
        size_t half = ws_size / 2;
        colC = (int)((half / ((size_t)K_DIM * 2) / 128) * 128);
        if (colC < 128) colC = 128;
        if (colC > N_DIM) colC = N_DIM;
        size_t rows = (ws_size - (size_t)colC * K_DIM * 2) / ((size_t)K_DIM * 2);
        rowC = (int)((rows / 128) * 128);
        if (rowC < 128) rowC = 128;
        if (rowC > M_DIM) rowC = M_DIM;
    }
    _Float16* W  = (_Float16*)d_ws;
    _Float16* Xh = (_Float16*)d_ws + (size_t)colC * K_DIM;

    for (int n0 = 0; n0 < N_DIM; n0 += colC) {
        int cols = N_DIM - n0; if (cols > colC) cols = colC;
        dequant_lora_kernel<<<cols / 4, 256, 0, stream>>>(q, sc, lA, lB, W, n0);
        for (int m0 = 0; m0 < M_DIM; m0 += rowC) {
            int rows = M_DIM - m0; if (rows > rowC) rows = rowC;
            convert_x_kernel<<<(int)(((size_t)rows * K_DIM) / (256 * 8)), 256, 0, stream>>>(
                x + (size_t)m0 * K_DIM, Xh);
            gemm_bt_kernel<<<(rows / 128) * (cols / 128), 256, 0, stream>>>(
                Xh, W, out, m0, n0, rows / 128, cols / 128);
        }
    }
}

// Round 6
// 621.562 us; speedup vs baseline: 1.3020x; 1.0133x over previous
//
#include <hip/hip_runtime.h>
#include <hip/hip_bf16.h>
#include <hip/hip_fp16.h>
#include <stdint.h>

// Problem constants (QLoRALinear_34454227649197)
#define M_DIM 16384   // TOK
#define N_DIM 4096    // OUT
#define K_DIM 4096    // IN
#define NGROUP 64     // K_DIM / 64
#define NT    64      // K-tiles (K_DIM / 64)

// Harness dtype note (round-3 forensics): float16 arrays are presented as
// FLOAT32 on device. x = const float*, out = float*.

typedef _Float16 f16x8 __attribute__((ext_vector_type(8)));
typedef _Float16 f16x2 __attribute__((ext_vector_type(2)));
typedef float f32x4 __attribute__((ext_vector_type(4)));

typedef __attribute__((address_space(3))) uint32_t lds_u32_t;
typedef const __attribute__((address_space(1))) uint32_t glob_u32_t;

__device__ __forceinline__ void gload16(const void* g, void* l) {
    // global_load_lds_dwordx4: LDS dest = wave-uniform base + lane*16;
    // global source is per-lane (pre-swizzled source, rule 21). Validated
    // correct rounds 1-5; zero bank conflicts measured round 5.
    __builtin_amdgcn_global_load_lds((glob_u32_t*)g, (lds_u32_t*)l, 16, 0, 0);
}

// ---------------------------------------------------------------------------
// Kernel 0: Xh[i] = (fp16) x[i]   (exact: x values are fp16-quantized)
// ---------------------------------------------------------------------------
__global__ __launch_bounds__(256) void convert_x_kernel(
    const float* __restrict__ x, _Float16* __restrict__ Xh)
{
    const size_t i = ((size_t)blockIdx.x * 256 + threadIdx.x) * 8;
    const float4 a = *reinterpret_cast<const float4*>(&x[i]);
    const float4 b = *reinterpret_cast<const float4*>(&x[i + 4]);
    f16x8 o;
    o[0] = (_Float16)a.x; o[1] = (_Float16)a.y;
    o[2] = (_Float16)a.z; o[3] = (_Float16)a.w;
    o[4] = (_Float16)b.x; o[5] = (_Float16)b.y;
    o[6] = (_Float16)b.z; o[7] = (_Float16)b.w;
    *reinterpret_cast<f16x8*>(&Xh[i]) = o;
}

// ---------------------------------------------------------------------------
// Kernel 1: W[local n][k] = (q[n0+n][k]-8)*scales[n0+n][k/64]
//                           + sum_r lB[n0+n][r]*lA[r][k]     (fp16 out)
// ---------------------------------------------------------------------------
__global__ __launch_bounds__(256) void dequant_lora_kernel(
    const int* __restrict__ q, const float* __restrict__ sc,
    const float* __restrict__ lA, const float* __restrict__ lB,
    _Float16* __restrict__ W, int n0)
{
    const int t   = threadIdx.x;
    const int o0l = blockIdx.x * 4;        // local chunk row base
    const int o0g = n0 + o0l;              // global OUT row base

    __shared__ float sScale[4][64];
    __shared__ float sB[4][16];
    sScale[t >> 6][t & 63] = sc[(size_t)(o0g + (t >> 6)) * NGROUP + (t & 63)];
    if (t < 64) sB[t >> 4][t & 15] = lB[(size_t)(o0g + (t >> 4)) * 16 + (t & 15)];
    __syncthreads();

    for (int j = 0; j < 8; ++j) {
        const int i = j * 512 + t * 2;      // even; covers [0,4096)
        float l0[4] = {0.f, 0.f, 0.f, 0.f};
        float l1[4] = {0.f, 0.f, 0.f, 0.f};
        #pragma unroll
        for (int r = 0; r < 16; ++r) {
            const float2 a = *reinterpret_cast<const float2*>(&lA[(size_t)r * K_DIM + i]);
            #pragma unroll
            for (int row = 0; row < 4; ++row) {
                l0[row] = fmaf(sB[row][r], a.x, l0[row]);
                l1[row] = fmaf(sB[row][r], a.y, l1[row]);
            }
        }
        const int g = i >> 6;               // i even => i, i+1 same group
        #pragma unroll
        for (int row = 0; row < 4; ++row) {
            const int2 qv = *reinterpret_cast<const int2*>(&q[(size_t)(o0g + row) * K_DIM + i]);
            const float s = sScale[row][g];
            f16x2 h2;
            h2[0] = (_Float16)fmaf((float)(qv.x - 8), s, l0[row]);
            h2[1] = (_Float16)fmaf((float)(qv.y - 8), s, l1[row]);
            *reinterpret_cast<f16x2*>(&W[(size_t)(o0l + row) * K_DIM + i]) = h2;
        }
    }
}

// ---------------------------------------------------------------------------
// Kernel 2: out = Xh @ W^T  — 3-buffer depth-2 pipeline (T3+T4+T5).
// BM=128, BN=256, BK=64, 512 thr = 8 waves (2M x 4N, 64x64 each).
// LDS: 3 x (A 16KB + B 32KB) = 144KB. Tile t+2 staged while computing t;
// vmcnt(6) = counted wait (tile t+1's 6 loads outstanding), one barrier/tile.
// Zero-conflict XOR swizzle from round 5 (pre-swizzled global source).
// ---------------------------------------------------------------------------
#define BUF_BYTES 49152   // 48 KiB per buffer (A 16K + B 16K+32K... A@0, B@16384)

__global__ __launch_bounds__(512, 2) void gemm_bt_kernel(
    const _Float16* __restrict__ A,   // Xh chunk, [rows][K]
    const _Float16* __restrict__ B,   // W chunk,  [cols][K]
    float* __restrict__ C,
    int m0, int n0, int nbm, int nbn)
{
    alignas(16) __shared__ _Float16 lds[3 * 24576];   // 144 KiB

    const int t  = threadIdx.x;
    const int l  = t & 63;
    const int w  = t >> 6;          // 0..7
    const int wr = w >> 2;          // 0..1  (M, 64 rows)
    const int wc = w & 3;           // 0..3  (N, 64 cols)

    // m204 bijective XCD swizzle, then tail-safe GROUP_M=8.
    const int nwg  = nbm * nbn;
    const int orig = blockIdx.x;
    const int xcd  = orig & 7;
    const int qq = nwg >> 3, rr = nwg & 7;
    const int wg = (xcd < rr ? xcd * (qq + 1) : rr * (qq + 1) + (xcd - rr) * qq)
                 + (orig >> 3);
    const int gs    = 8 * nbn;
    const int group = wg / gs;
    const int start = group * 8;
    const int gsz   = (nbm - start < 8) ? (nbm - start) : 8;
    const int idg   = wg - group * gs;
    const int bm    = start + idg % gsz;
    const int bn    = idg / gsz;

    const int Mb = bm * 128;        // row within A chunk
    const int Nb = bn * 256;        // row within W chunk

    // Staging: 512 thr x 16B = 8KB/issue = 64 rows x 128B. Thread t -> row
    // rloc = t>>3, physical slot t&7; source k-off = ((t&7)^(rloc&7))*8.
    const int rloc = t >> 3;                   // 0..63
    const int kswz = ((t & 7) ^ (rloc & 7)) * 8;
    const _Float16* aSrc = A + (size_t)(Mb + rloc) * K_DIM + kswz;
    const _Float16* bSrc = B + (size_t)(Nb + rloc) * K_DIM + kswz;
    char* const ldsBase = (char*)lds;
    const int dOff = t * 16;

    const int r16 = l & 15;
    const int hi  = l >> 4;         // 0..3

    f32x4 acc[4][4] = {};

    // --- prologue: stage tiles 0 and 1 into buffers 0,1 (12 loads out) ---
    #pragma unroll
    for (int tt0 = 0; tt0 < 2; ++tt0) {
        char* d = ldsBase + tt0 * BUF_BYTES + dOff;
        const int k0 = tt0 * 64;
        gload16(aSrc + (size_t)0 * 64 * K_DIM + k0, d);
        gload16(aSrc + (size_t)1 * 64 * K_DIM + k0, d + 8192);
        gload16(bSrc + (size_t)0 * 64 * K_DIM + k0, d + 16384);
        gload16(bSrc + (size_t)1 * 64 * K_DIM + k0, d + 24576);
        gload16(bSrc + (size_t)2 * 64 * K_DIM + k0, d + 32768);
        gload16(bSrc + (size_t)3 * 64 * K_DIM + k0, d + 40960);
    }

    int cur = 0;                    // buffer of tile tt
    int pre = 2;                    // buffer of tile tt+2

    for (int tt = 0; tt < NT; ++tt) {
        // Counted wait: own tile-tt loads landed (t+1's 6 may stay in flight).
        if (tt < NT - 1) asm volatile("s_waitcnt vmcnt(6)" ::: "memory");
        else             asm volatile("s_waitcnt vmcnt(0)" ::: "memory");
        __builtin_amdgcn_s_barrier();          // all waves' tile-tt loads landed
        __builtin_amdgcn_sched_barrier(0);     // nothing hoists above barrier

        const char* Ac = ldsBase + cur * BUF_BYTES;
        const char* Bc = Ac + 16384;
        char* dp = ldsBase + pre * BUF_BYTES + dOff;
        const bool pf = (tt + 2) < NT;
        const int kp = (tt + 2) * 64;

        // ---- phase 0: prefetch A + B0, read kstep 0, 16 MFMA ----
        if (pf) {
            gload16(aSrc + (size_t)0 * 64 * K_DIM + kp, dp);
            gload16(aSrc + (size_t)1 * 64 * K_DIM + kp, dp + 8192);
            gload16(bSrc + (size_t)0 * 64 * K_DIM + kp, dp + 16384);
        }
        {
            f16x8 aF[4], bF[4];
            const int swz = (hi ^ (r16 & 7)) * 16;       // kstep 0
            #pragma unroll
            for (int i = 0; i < 4; ++i) {
                aF[i] = *(const f16x8*)(Ac + (wr * 64 + i * 16 + r16) * 128 + swz);
                bF[i] = *(const f16x8*)(Bc + (wc * 64 + i * 16 + r16) * 128 + swz);
            }
            __builtin_amdgcn_s_setprio(1);
            #pragma unroll
            for (int mi = 0; mi < 4; ++mi)
                #pragma unroll
                for (int ni = 0; ni < 4; ++ni)
                    acc[mi][ni] = __builtin_amdgcn_mfma_f32_16x16x32_f16(
                        aF[mi], bF[ni], acc[mi][ni], 0, 0, 0);
            __builtin_amdgcn_s_setprio(0);
        }

        // ---- phase 1: prefetch B1-B3, read kstep 1, 16 MFMA ----
        if (pf) {
            gload16(bSrc + (size_t)1 * 64 * K_DIM + kp, dp + 24576);
            gload16(bSrc + (size_t)2 * 64 * K_DIM + kp, dp + 32768);
            gload16(bSrc + (size_t)3 * 64 * K_DIM + kp, dp + 40960);
        }
        {
            f16x8 aF[4], bF[4];
            const int swz = ((4 + hi) ^ (r16 & 7)) * 16; // kstep 1
            #pragma unroll
            for (int i = 0; i < 4; ++i) {
                aF[i] = *(const f16x8*)(Ac + (wr * 64 + i * 16 + r16) * 128 + swz);
                bF[i] = *(const f16x8*)(Bc + (wc * 64 + i * 16 + r16) * 128 + swz);
            }
            __builtin_amdgcn_s_setprio(1);
            #pragma unroll
            for (int mi = 0; mi < 4; ++mi)
                #pragma unroll
                for (int ni = 0; ni < 4; ++ni)
                    acc[mi][ni] = __builtin_amdgcn_mfma_f32_16x16x32_f16(
                        aF[mi], bF[ni], acc[mi][ni], 0, 0, 0);
            __builtin_amdgcn_s_setprio(0);
        }

        cur = (cur == 2) ? 0 : cur + 1;
        pre = (pre == 2) ? 0 : pre + 1;
    }

    // Epilogue: C/D layout col = lane&15, row = (lane>>4)*4 + reg. f32 stores.
    #pragma unroll
    for (int mi = 0; mi < 4; ++mi) {
        const int row0 = m0 + Mb + wr * 64 + mi * 16 + hi * 4;
        #pragma unroll
        for (int ni = 0; ni < 4; ++ni) {
            const int col = n0 + Nb + wc * 64 + ni * 16 + r16;
            const f32x4 v = acc[mi][ni];
            #pragma unroll
            for (int u = 0; u < 4; ++u)
                C[(size_t)(row0 + u) * N_DIM + col] = v[u];
        }
    }
}

extern "C" void kernel_launch(void* const* d_in, const int* in_sizes, int n_in,
                              void* d_out, int out_size, void* d_ws, size_t ws_size,
                              hipStream_t stream) {
    const float* x  = (const float*)d_in[0];   // fp16 values promoted to f32
    const int*   q  = (const int*)d_in[1];
    const float* sc = (const float*)d_in[2];
    const float* lA = (const float*)d_in[3];
    const float* lB = (const float*)d_in[4];
    float* out = (float*)d_out;                 // f32 output buffer

    // Workspace layout: [W: colC x K fp16][Xh: rowC x K fp16], chunk-looped.
    // colC multiple of 256 (BN), rowC multiple of 128 (BM).
    const size_t wfull = (size_t)N_DIM * K_DIM * 2;   // 32 MiB
    int colC, rowC;
    if (ws_size >= wfull + (size_t)128 * K_DIM * 2) {
        colC = N_DIM;
        size_t rows = (ws_size - wfull) / ((size_t)K_DIM * 2);
        rowC = (int)((rows / 128) * 128);
        if (rowC > M_DIM) rowC = M_DIM;
    } else {
        size_t half = ws_size / 2;
        colC = (int)((half / ((size_t)K_DIM * 2) / 256) * 256);
        if (colC < 256) colC = 256;
        if (colC > N_DIM) colC = N_DIM;
        size_t rows = (ws_size - (size_t)colC * K_DIM * 2) / ((size_t)K_DIM * 2);
        rowC = (int)((rows / 128) * 128);
        if (rowC < 128) rowC = 128;
        if (rowC > M_DIM) rowC = M_DIM;
    }
    _Float16* W  = (_Float16*)d_ws;
    _Float16* Xh = (_Float16*)d_ws + (size_t)colC * K_DIM;

    for (int n0 = 0; n0 < N_DIM; n0 += colC) {
        int cols = N_DIM - n0; if (cols > colC) cols = colC;
        dequant_lora_kernel<<<cols / 4, 256, 0, stream>>>(q, sc, lA, lB, W, n0);
        for (int m0 = 0; m0 < M_DIM; m0 += rowC) {
            int rows = M_DIM - m0; if (rows > rowC) rows = rowC;
            convert_x_kernel<<<(int)(((size_t)rows * K_DIM) / (256 * 8)), 256, 0, stream>>>(
                x + (size_t)m0 * K_DIM, Xh);
            gemm_bt_kernel<<<(rows / 128) * (cols / 256), 512, 0, stream>>>(
                Xh, W, out, m0, n0, rows / 128, cols / 256);
        }
    }
}

// Round 7
// 603.383 us; speedup vs baseline: 1.3412x; 1.0301x over previous
//
#include <hip/hip_runtime.h>
#include <hip/hip_bf16.h>
#include <hip/hip_fp16.h>
#include <stdint.h>

// Problem constants (QLoRALinear_34454227649197)
#define M_DIM 16384   // TOK
#define N_DIM 4096    // OUT
#define K_DIM 4096    // IN
#define NGROUP 64     // K_DIM / 64
#define NT    64      // K-tiles (K_DIM / 64)

// Harness dtype note (round-3 forensics): float16 arrays are presented as
// FLOAT32 on device. x = const float*, out = float*.

typedef _Float16 f16x8 __attribute__((ext_vector_type(8)));
typedef _Float16 f16x2 __attribute__((ext_vector_type(2)));
typedef float f32x4 __attribute__((ext_vector_type(4)));

typedef __attribute__((address_space(3))) uint32_t lds_u32_t;
typedef const __attribute__((address_space(1))) uint32_t glob_u32_t;

__device__ __forceinline__ void gload16(const void* g, void* l) {
    // global_load_lds_dwordx4: LDS dest = wave-uniform base + lane*16;
    // global source is per-lane (pre-swizzled source). Validated rounds 1-6;
    // zero bank conflicts measured rounds 5-6.
    __builtin_amdgcn_global_load_lds((glob_u32_t*)g, (lds_u32_t*)l, 16, 0, 0);
}

// ---------------------------------------------------------------------------
// Kernel 0: Xh[i] = (fp16) x[i]   (exact: x values are fp16-quantized)
// ---------------------------------------------------------------------------
__global__ __launch_bounds__(256) void convert_x_kernel(
    const float* __restrict__ x, _Float16* __restrict__ Xh)
{
    const size_t i = ((size_t)blockIdx.x * 256 + threadIdx.x) * 8;
    const float4 a = *reinterpret_cast<const float4*>(&x[i]);
    const float4 b = *reinterpret_cast<const float4*>(&x[i + 4]);
    f16x8 o;
    o[0] = (_Float16)a.x; o[1] = (_Float16)a.y;
    o[2] = (_Float16)a.z; o[3] = (_Float16)a.w;
    o[4] = (_Float16)b.x; o[5] = (_Float16)b.y;
    o[6] = (_Float16)b.z; o[7] = (_Float16)b.w;
    *reinterpret_cast<f16x8*>(&Xh[i]) = o;
}

// ---------------------------------------------------------------------------
// Kernel 1: W[local n][k] = (q[n0+n][k]-8)*scales[n0+n][k/64]
//                           + sum_r lB[n0+n][r]*lA[r][k]     (fp16 out)
// ---------------------------------------------------------------------------
__global__ __launch_bounds__(256) void dequant_lora_kernel(
    const int* __restrict__ q, const float* __restrict__ sc,
    const float* __restrict__ lA, const float* __restrict__ lB,
    _Float16* __restrict__ W, int n0)
{
    const int t   = threadIdx.x;
    const int o0l = blockIdx.x * 4;        // local chunk row base
    const int o0g = n0 + o0l;              // global OUT row base

    __shared__ float sScale[4][64];
    __shared__ float sB[4][16];
    sScale[t >> 6][t & 63] = sc[(size_t)(o0g + (t >> 6)) * NGROUP + (t & 63)];
    if (t < 64) sB[t >> 4][t & 15] = lB[(size_t)(o0g + (t >> 4)) * 16 + (t & 15)];
    __syncthreads();

    for (int j = 0; j < 8; ++j) {
        const int i = j * 512 + t * 2;      // even; covers [0,4096)
        float l0[4] = {0.f, 0.f, 0.f, 0.f};
        float l1[4] = {0.f, 0.f, 0.f, 0.f};
        #pragma unroll
        for (int r = 0; r < 16; ++r) {
            const float2 a = *reinterpret_cast<const float2*>(&lA[(size_t)r * K_DIM + i]);
            #pragma unroll
            for (int row = 0; row < 4; ++row) {
                l0[row] = fmaf(sB[row][r], a.x, l0[row]);
                l1[row] = fmaf(sB[row][r], a.y, l1[row]);
            }
        }
        const int g = i >> 6;               // i even => i, i+1 same group
        #pragma unroll
        for (int row = 0; row < 4; ++row) {
            const int2 qv = *reinterpret_cast<const int2*>(&q[(size_t)(o0g + row) * K_DIM + i]);
            const float s = sScale[row][g];
            f16x2 h2;
            h2[0] = (_Float16)fmaf((float)(qv.x - 8), s, l0[row]);
            h2[1] = (_Float16)fmaf((float)(qv.y - 8), s, l1[row]);
            *reinterpret_cast<f16x2*>(&W[(size_t)(o0l + row) * K_DIM + i]) = h2;
        }
    }
}

// ---------------------------------------------------------------------------
// Kernel 2: out = Xh @ W^T — 256x256 tile, BK=64, 512 thr = 8 waves (2M x 4N,
// each wave 128x64 output = 8x4 fragments -> 384 B LDS-read per MFMA, the
// m201 reuse ratio). 2 LDS dbuf (128 KB), prefetch 1 tile ahead; per-tile
// compute (~2480 cyc) >> HBM latency so the tile-top __syncthreads' vmcnt(0)
// finds loads already landed. Zero-conflict XOR swizzle (rounds 5-6).
// ---------------------------------------------------------------------------
#define ABUF 32768                    // A: 256 rows x 128 B
#define BUF_BYTES 65536               // A (32K) + B (32K)

__global__ __launch_bounds__(512, 2) void gemm_bt_kernel(
    const _Float16* __restrict__ A,   // Xh chunk, [rows][K]
    const _Float16* __restrict__ B,   // W chunk,  [cols][K]
    float* __restrict__ C,
    int m0, int n0, int nbm, int nbn)
{
    alignas(16) __shared__ _Float16 lds[2 * 32768];   // 128 KiB

    const int t  = threadIdx.x;
    const int l  = t & 63;
    const int w  = t >> 6;          // 0..7
    const int wr = w >> 2;          // 0..1  (M: 128 rows)
    const int wc = w & 3;           // 0..3  (N: 64 cols)

    // m204 bijective XCD swizzle, then tail-safe GROUP_M=8.
    const int nwg  = nbm * nbn;
    const int orig = blockIdx.x;
    const int xcd  = orig & 7;
    const int qq = nwg >> 3, rr = nwg & 7;
    const int wg = (xcd < rr ? xcd * (qq + 1) : rr * (qq + 1) + (xcd - rr) * qq)
                 + (orig >> 3);
    const int gs    = 8 * nbn;
    const int group = wg / gs;
    const int start = group * 8;
    const int gsz   = (nbm - start < 8) ? (nbm - start) : 8;
    const int idg   = wg - group * gs;
    const int bm    = start + idg % gsz;
    const int bn    = idg / gsz;

    const int Mb = bm * 256;        // row within A chunk
    const int Nb = bn * 256;        // row within W chunk

    // Staging: 512 thr x 16B = 8 KB = 64 rows x 128 B per issue; 4 issues per
    // operand per K-tile. Thread t -> local row t>>3, phys slot t&7; source
    // k-off = ((t&7)^(rloc&7))*8 (inverse swizzle on global side).
    const int rloc = t >> 3;                   // 0..63
    const int kswz = ((t & 7) ^ (rloc & 7)) * 8;
    const _Float16* aSrc = A + (size_t)(Mb + rloc) * K_DIM + kswz;
    const _Float16* bSrc = B + (size_t)(Nb + rloc) * K_DIM + kswz;
    char* const ldsBase = (char*)lds;
    const int dOff = t * 16;

    const int r16 = l & 15;
    const int hi  = l >> 4;         // 0..3
    const int swzB = (r16 & 7) * 16;  // row-dependent XOR part (bytes)

    f32x4 acc[8][4] = {};

    // --- prologue: stage tile 0 into buf 0 ---
    {
        char* d = ldsBase + dOff;
        #pragma unroll
        for (int n = 0; n < 4; ++n) {
            gload16(aSrc + (size_t)(n * 64) * K_DIM, d + n * 8192);
            gload16(bSrc + (size_t)(n * 64) * K_DIM, d + ABUF + n * 8192);
        }
    }

    for (int kt = 0; kt < NT; ++kt) {
        __syncthreads();   // vmcnt(0)+lgkmcnt(0)+barrier: tile kt published.
                           // Own tile-kt loads were issued one full tile ago
                           // (~2480 cyc of compute) -> drain is ~free.
        const char* Ac = ldsBase + (kt & 1) * BUF_BYTES;
        const char* Bc = Ac + ABUF;

        // Issue next tile's 8 loads into the other buffer (disjoint from all
        // live reads; previous reads of that buffer finished before the
        // barrier above).
        if (kt + 1 < NT) {
            char* d = ldsBase + ((kt + 1) & 1) * BUF_BYTES + dOff;
            const int kp = (kt + 1) * 64;
            #pragma unroll
            for (int n = 0; n < 4; ++n) {
                gload16(aSrc + (size_t)(n * 64) * K_DIM + kp, d + n * 8192);
                gload16(bSrc + (size_t)(n * 64) * K_DIM + kp, d + ABUF + n * 8192);
            }
        }

        // 4 phases: (ks, mq); bF reused across the two mq phases of each ks.
        #pragma unroll
        for (int ks = 0; ks < 2; ++ks) {
            f16x8 bF[4];
            const int swz = ((ks * 4 + hi) * 16) ^ swzB;   // phys slot bytes
            #pragma unroll
            for (int i = 0; i < 4; ++i)
                bF[i] = *(const f16x8*)(Bc + (wc * 64 + i * 16 + r16) * 128 + swz);
            #pragma unroll
            for (int mq = 0; mq < 2; ++mq) {
                f16x8 aF[4];
                #pragma unroll
                for (int i = 0; i < 4; ++i)
                    aF[i] = *(const f16x8*)(Ac + (wr * 128 + mq * 64 + i * 16 + r16) * 128 + swz);
                __builtin_amdgcn_s_setprio(1);
                #pragma unroll
                for (int mi = 0; mi < 4; ++mi)
                    #pragma unroll
                    for (int ni = 0; ni < 4; ++ni)
                        acc[mq * 4 + mi][ni] = __builtin_amdgcn_mfma_f32_16x16x32_f16(
                            aF[mi], bF[ni], acc[mq * 4 + mi][ni], 0, 0, 0);
                __builtin_amdgcn_s_setprio(0);
            }
        }
    }

    // Epilogue: C/D layout col = lane&15, row = (lane>>4)*4 + reg. f32 stores.
    #pragma unroll
    for (int mi = 0; mi < 8; ++mi) {
        const int row0 = m0 + Mb + wr * 128 + mi * 16 + hi * 4;
        #pragma unroll
        for (int ni = 0; ni < 4; ++ni) {
            const int col = n0 + Nb + wc * 64 + ni * 16 + r16;
            const f32x4 v = acc[mi][ni];
            #pragma unroll
            for (int u = 0; u < 4; ++u)
                C[(size_t)(row0 + u) * N_DIM + col] = v[u];
        }
    }
}

extern "C" void kernel_launch(void* const* d_in, const int* in_sizes, int n_in,
                              void* d_out, int out_size, void* d_ws, size_t ws_size,
                              hipStream_t stream) {
    const float* x  = (const float*)d_in[0];   // fp16 values promoted to f32
    const int*   q  = (const int*)d_in[1];
    const float* sc = (const float*)d_in[2];
    const float* lA = (const float*)d_in[3];
    const float* lB = (const float*)d_in[4];
    float* out = (float*)d_out;                 // f32 output buffer

    // Workspace layout: [W: colC x K fp16][Xh: rowC x K fp16], chunk-looped.
    // colC, rowC multiples of 256 (BM=BN=256).
    const size_t wfull = (size_t)N_DIM * K_DIM * 2;   // 32 MiB
    int colC, rowC;
    if (ws_size >= wfull + (size_t)256 * K_DIM * 2) {
        colC = N_DIM;
        size_t rows = (ws_size - wfull) / ((size_t)K_DIM * 2);
        rowC = (int)((rows / 256) * 256);
        if (rowC > M_DIM) rowC = M_DIM;
    } else {
        size_t half = ws_size / 2;
        colC = (int)((half / ((size_t)K_DIM * 2) / 256) * 256);
        if (colC < 256) colC = 256;
        if (colC > N_DIM) colC = N_DIM;
        size_t rows = (ws_size - (size_t)colC * K_DIM * 2) / ((size_t)K_DIM * 2);
        rowC = (int)((rows / 256) * 256);
        if (rowC < 256) rowC = 256;
        if (rowC > M_DIM) rowC = M_DIM;
    }
    _Float16* W  = (_Float16*)d_ws;
    _Float16* Xh = (_Float16*)d_ws + (size_t)colC * K_DIM;

    for (int n0 = 0; n0 < N_DIM; n0 += colC) {
        int cols = N_DIM - n0; if (cols > colC) cols = colC;
        dequant_lora_kernel<<<cols / 4, 256, 0, stream>>>(q, sc, lA, lB, W, n0);
        for (int m0 = 0; m0 < M_DIM; m0 += rowC) {
            int rows = M_DIM - m0; if (rows > rowC) rows = rowC;
            convert_x_kernel<<<(int)(((size_t)rows * K_DIM) / (256 * 8)), 256, 0, stream>>>(
                x + (size_t)m0 * K_DIM, Xh);
            gemm_bt_kernel<<<(rows / 256) * (cols / 256), 512, 0, stream>>>(
                Xh, W, out, m0, n0, rows / 256, cols / 256);
        }
    }
}